// Round 11
// baseline (1276.240 us; speedup 1.0000x reference)
//
#include <hip/hip_runtime.h>
#include <math.h>

#define CC 256       // channels = HEADS * HD
#define HEADS 4
#define HD 64
#define NG 64        // num graphs
#define SCAN_BS 512
#define QKVS 768     // fused QKV row stride
#define LDK 40       // padded LDS k-stride (bf16 elems)

typedef __attribute__((ext_vector_type(8))) short s16x8;   // 8 x bf16 (4 VGPRs)
typedef __attribute__((ext_vector_type(4))) float f32x4;

static __device__ __forceinline__ float bf2f(unsigned short u) {
  return (float)__builtin_bit_cast(__bf16, u);
}

// ---------------- CSR build (by dst) ----------------
__global__ void hist_kernel(const int* __restrict__ dst, int* __restrict__ deg, int E) {
  int e = blockIdx.x * blockDim.x + threadIdx.x;
  if (e < E) atomicAdd(&deg[dst[e]], 1);
}

__global__ void scan1_kernel(const int* __restrict__ deg, int* __restrict__ exc,
                             int* __restrict__ partial, int n) {
  __shared__ int s[SCAN_BS];
  int t = threadIdx.x;
  int g = blockIdx.x * SCAN_BS + t;
  int v = (g < n) ? deg[g] : 0;
  s[t] = v;
  __syncthreads();
  for (int off = 1; off < SCAN_BS; off <<= 1) {
    int add = (t >= off) ? s[t - off] : 0;
    __syncthreads();
    s[t] += add;
    __syncthreads();
  }
  if (g < n) exc[g] = s[t] - v;
  if (t == SCAN_BS - 1) partial[blockIdx.x] = s[t];
}

__global__ void scan2_kernel(int* __restrict__ partial, int nb) {
  __shared__ int s[SCAN_BS];
  int t = threadIdx.x;
  int v = (t < nb) ? partial[t] : 0;
  s[t] = v;
  __syncthreads();
  for (int off = 1; off < SCAN_BS; off <<= 1) {
    int add = (t >= off) ? s[t - off] : 0;
    __syncthreads();
    s[t] += add;
    __syncthreads();
  }
  if (t < nb) partial[t] = s[t] - v;
}

__global__ void scan3_kernel(const int* __restrict__ exc, const int* __restrict__ partial,
                             int* __restrict__ row_start, int* __restrict__ cursor,
                             int n, int E) {
  int g = blockIdx.x * blockDim.x + threadIdx.x;
  if (g < n) {
    int v = exc[g] + partial[g / SCAN_BS];
    row_start[g] = v;
    cursor[g] = v;
  }
  if (g == n) row_start[n] = E;
}

__global__ void scatter_kernel(const int* __restrict__ srcArr, const int* __restrict__ dstArr,
                               int* __restrict__ cursor, int* __restrict__ csr_src, int E) {
  int e = blockIdx.x * blockDim.x + threadIdx.x;
  if (e < E) {
    int d = dstArr[e];
    int p = atomicAdd(&cursor[d], 1);
    csr_src[p] = srcArr[e];
  }
}

// ---------------- weight prep: transpose + concat + bf16 hi/lo split ----------------
__global__ void wprep_kernel(const float* __restrict__ Wq, const float* __restrict__ Wk,
                             const float* __restrict__ Wv, const float* __restrict__ bq,
                             const float* __restrict__ bk, const float* __restrict__ bv,
                             unsigned short* __restrict__ Bth, unsigned short* __restrict__ Btl,
                             float* __restrict__ biascat, int L) {
  int idx = blockIdx.x * 256 + threadIdx.x;
  int total = L * QKVS * CC;
  if (idx >= total) return;
  int k = idx & 255;
  int n = (idx >> 8) % QKVS;
  int l = idx / (QKVS * CC);
  int part = n >> 8;
  int nn = n & 255;
  const float* W = part == 0 ? Wq : (part == 1 ? Wk : Wv);
  float v = W[((long)l * CC + k) * CC + nn];
  __bf16 h = (__bf16)v;
  Bth[idx] = __builtin_bit_cast(unsigned short, h);
  Btl[idx] = __builtin_bit_cast(unsigned short, (__bf16)(v - (float)h));
  if (k == 0) {
    const float* bb = part == 0 ? bq : (part == 1 ? bk : bv);
    biascat[l * QKVS + n] = bb[l * CC + nn];
  }
}

// ---------------- activation split: fp32 -> bf16 hi + lo (layer-0 input only) ------
__global__ void split_kernel(const float* __restrict__ in, unsigned short* __restrict__ hi,
                             unsigned short* __restrict__ lo, int n4) {
  int i = blockIdx.x * 256 + threadIdx.x;
  if (i >= n4) return;
  float4 v = ((const float4*)in)[i];
  __bf16 h0 = (__bf16)v.x, h1 = (__bf16)v.y, h2 = (__bf16)v.z, h3 = (__bf16)v.w;
  ushort4 hv = make_ushort4(__builtin_bit_cast(unsigned short, h0),
                            __builtin_bit_cast(unsigned short, h1),
                            __builtin_bit_cast(unsigned short, h2),
                            __builtin_bit_cast(unsigned short, h3));
  ushort4 lv = make_ushort4(__builtin_bit_cast(unsigned short, (__bf16)(v.x - (float)h0)),
                            __builtin_bit_cast(unsigned short, (__bf16)(v.y - (float)h1)),
                            __builtin_bit_cast(unsigned short, (__bf16)(v.z - (float)h2)),
                            __builtin_bit_cast(unsigned short, (__bf16)(v.w - (float)h3)));
  ((ushort4*)hi)[i] = hv;
  ((ushort4*)lo)[i] = lv;
}

// ---------------- fused QKV GEMM via split-bf16 MFMA ----------------
__global__ __launch_bounds__(256) void qkv_gemm(const unsigned short* __restrict__ Ah,
                                                const unsigned short* __restrict__ Al,
                                                const unsigned short* __restrict__ Bh,
                                                const unsigned short* __restrict__ Bl,
                                                const float* __restrict__ biascat,
                                                float* __restrict__ C, int M) {
  __shared__ unsigned short As_h[128 * LDK], As_l[128 * LDK];
  __shared__ unsigned short Bs_h[128 * LDK], Bs_l[128 * LDK];
  int t = threadIdx.x;
  int bm = blockIdx.x, bn = blockIdx.y;
  int lane = t & 63, wave = t >> 6;
  int mo = (wave >> 1) * 64, no = (wave & 1) * 64;
  int col_l = lane & 15, q = lane >> 4;

  f32x4 acc[4][4];
#pragma unroll
  for (int i = 0; i < 4; ++i)
#pragma unroll
    for (int j = 0; j < 4; ++j) acc[i][j] = (f32x4)0.f;

  int sr = t >> 1;
  int sh = (t & 1) * 16;
  long arow = (long)bm * 128 + sr;
  bool aval = arow < M;
  const unsigned short* agh = Ah + arow * CC + sh;
  const unsigned short* agl = Al + arow * CC + sh;
  const unsigned short* bgh = Bh + ((long)bn * 128 + sr) * CC + sh;
  const unsigned short* bgl = Bl + ((long)bn * 128 + sr) * CC + sh;
  uint4 zz = make_uint4(0, 0, 0, 0);

  for (int kt = 0; kt < CC; kt += 32) {
    uint4 ah0 = zz, ah1 = zz, al0 = zz, al1 = zz;
    if (aval) {
      ah0 = *(const uint4*)(agh + kt);
      ah1 = *(const uint4*)(agh + kt + 8);
      al0 = *(const uint4*)(agl + kt);
      al1 = *(const uint4*)(agl + kt + 8);
    }
    uint4 bh0 = *(const uint4*)(bgh + kt);
    uint4 bh1 = *(const uint4*)(bgh + kt + 8);
    uint4 bl0 = *(const uint4*)(bgl + kt);
    uint4 bl1 = *(const uint4*)(bgl + kt + 8);
    __syncthreads();
    *(uint4*)&As_h[sr * LDK + sh] = ah0;
    *(uint4*)&As_h[sr * LDK + sh + 8] = ah1;
    *(uint4*)&As_l[sr * LDK + sh] = al0;
    *(uint4*)&As_l[sr * LDK + sh + 8] = al1;
    *(uint4*)&Bs_h[sr * LDK + sh] = bh0;
    *(uint4*)&Bs_h[sr * LDK + sh + 8] = bh1;
    *(uint4*)&Bs_l[sr * LDK + sh] = bl0;
    *(uint4*)&Bs_l[sr * LDK + sh + 8] = bl1;
    __syncthreads();

    s16x8 afh[4], afl[4], bfh[4], bfl[4];
#pragma unroll
    for (int i = 0; i < 4; ++i) {
      int am = mo + i * 16 + col_l;
      afh[i] = *(const s16x8*)&As_h[am * LDK + q * 8];
      afl[i] = *(const s16x8*)&As_l[am * LDK + q * 8];
      int bnn = no + i * 16 + col_l;
      bfh[i] = *(const s16x8*)&Bs_h[bnn * LDK + q * 8];
      bfl[i] = *(const s16x8*)&Bs_l[bnn * LDK + q * 8];
    }
#pragma unroll
    for (int i = 0; i < 4; ++i)
#pragma unroll
      for (int j = 0; j < 4; ++j) {
        acc[i][j] = __builtin_amdgcn_mfma_f32_16x16x32_bf16(afh[i], bfh[j], acc[i][j], 0, 0, 0);
        acc[i][j] = __builtin_amdgcn_mfma_f32_16x16x32_bf16(afh[i], bfl[j], acc[i][j], 0, 0, 0);
        acc[i][j] = __builtin_amdgcn_mfma_f32_16x16x32_bf16(afl[i], bfh[j], acc[i][j], 0, 0, 0);
      }
  }

  long rbase = (long)bm * 128 + mo;
  int cbase = bn * 128 + no;
#pragma unroll
  for (int j = 0; j < 4; ++j) {
    int col = cbase + j * 16 + col_l;
    float bias = biascat[col];
#pragma unroll
    for (int i = 0; i < 4; ++i) {
#pragma unroll
      for (int r = 0; r < 4; ++r) {
        long row = rbase + i * 16 + q * 4 + r;
        if (row < M) C[row * QKVS + col] = acc[i][j][r] + bias;
      }
    }
  }
}

// ---------------- fused attention: wave = node ----------------
// block = 4 nodes (XCD-swizzled), wave owns one node end-to-end: no LDS merge,
// no __syncthreads, no idle waves at mean deg=16. lane = (head=lane>>4, dim4=lane&15);
// one wave computes all 4 heads per edge via 4-step 16-lane dot-reduce.
// 8-edge chunks keep 16 K/V row loads in flight (K and V fetched together).
__global__ __launch_bounds__(256) void attn_fused_kernel(const float* __restrict__ qkv,
                                                         const int* __restrict__ row_start,
                                                         const int* __restrict__ csr_src,
                                                         unsigned short* __restrict__ h_hi,
                                                         unsigned short* __restrict__ h_lo,
                                                         int N, int npx) {
  int b = blockIdx.x;
  int nb = (b & 7) * npx + (b >> 3);
  int wave = threadIdx.x >> 6;
  int lane = threadIdx.x & 63;
  int node = nb * 4 + wave;
  if (node >= N) return;
  int s0 = row_start[node], s1 = row_start[node + 1];

  const f32x4 q4 = *(const f32x4*)(qkv + (size_t)node * QKVS + lane * 4);

  float m = -1e30f, z = 0.f;
  f32x4 acc = (f32x4)0.f;

  int i = s0;
  for (; i + 8 <= s1; i += 8) {
    int ix[8];
#pragma unroll
    for (int u = 0; u < 8; ++u) ix[u] = csr_src[i + u];
    f32x4 kk[8], vv[8];
#pragma unroll
    for (int u = 0; u < 8; ++u) {
      const float* row = qkv + (size_t)ix[u] * QKVS;
      kk[u] = *(const f32x4*)(row + 256 + lane * 4);
      vv[u] = *(const f32x4*)(row + 512 + lane * 4);
    }
    float lg[8];
#pragma unroll
    for (int u = 0; u < 8; ++u) {
      float d = q4.x * kk[u].x + q4.y * kk[u].y + q4.z * kk[u].z + q4.w * kk[u].w;
#pragma unroll
      for (int off = 1; off < 16; off <<= 1) d += __shfl_xor(d, off, 64);
      lg[u] = d * 0.125f;
    }
    float cm = lg[0];
#pragma unroll
    for (int u = 1; u < 8; ++u) cm = fmaxf(cm, lg[u]);
    float mn = fmaxf(m, cm);
    float sc = __expf(m - mn);
    z *= sc;
    acc *= sc;
    m = mn;
#pragma unroll
    for (int u = 0; u < 8; ++u) {
      float e = __expf(lg[u] - m);
      z += e;
      acc += e * vv[u];
    }
  }
  for (; i + 4 <= s1; i += 4) {
    int ix[4];
#pragma unroll
    for (int u = 0; u < 4; ++u) ix[u] = csr_src[i + u];
    f32x4 kk[4], vv[4];
#pragma unroll
    for (int u = 0; u < 4; ++u) {
      const float* row = qkv + (size_t)ix[u] * QKVS;
      kk[u] = *(const f32x4*)(row + 256 + lane * 4);
      vv[u] = *(const f32x4*)(row + 512 + lane * 4);
    }
    float lg[4];
#pragma unroll
    for (int u = 0; u < 4; ++u) {
      float d = q4.x * kk[u].x + q4.y * kk[u].y + q4.z * kk[u].z + q4.w * kk[u].w;
#pragma unroll
      for (int off = 1; off < 16; off <<= 1) d += __shfl_xor(d, off, 64);
      lg[u] = d * 0.125f;
    }
    float cm = fmaxf(fmaxf(lg[0], lg[1]), fmaxf(lg[2], lg[3]));
    float mn = fmaxf(m, cm);
    float sc = __expf(m - mn);
    z *= sc;
    acc *= sc;
    m = mn;
#pragma unroll
    for (int u = 0; u < 4; ++u) {
      float e = __expf(lg[u] - m);
      z += e;
      acc += e * vv[u];
    }
  }
  for (; i < s1; ++i) {
    int s = csr_src[i];
    const float* row = qkv + (size_t)s * QKVS;
    f32x4 k4 = *(const f32x4*)(row + 256 + lane * 4);
    f32x4 v4 = *(const f32x4*)(row + 512 + lane * 4);
    float d = q4.x * k4.x + q4.y * k4.y + q4.z * k4.z + q4.w * k4.w;
#pragma unroll
    for (int off = 1; off < 16; off <<= 1) d += __shfl_xor(d, off, 64);
    float lgs = d * 0.125f;
    float mn = fmaxf(m, lgs);
    float sc = __expf(m - mn);
    float e = __expf(lgs - mn);
    z = z * sc + e;
    acc = acc * sc + e * v4;
    m = mn;
  }

  float rz = 1.f / (z + 1e-16f);
  float o0 = fmaxf(acc.x * rz, 0.f);
  float o1 = fmaxf(acc.y * rz, 0.f);
  float o2 = fmaxf(acc.z * rz, 0.f);
  float o3 = fmaxf(acc.w * rz, 0.f);
  __bf16 h0 = (__bf16)o0, h1 = (__bf16)o1, h2 = (__bf16)o2, h3 = (__bf16)o3;
  ushort4 ohi = make_ushort4(__builtin_bit_cast(unsigned short, h0),
                             __builtin_bit_cast(unsigned short, h1),
                             __builtin_bit_cast(unsigned short, h2),
                             __builtin_bit_cast(unsigned short, h3));
  ushort4 olo = make_ushort4(__builtin_bit_cast(unsigned short, (__bf16)(o0 - (float)h0)),
                             __builtin_bit_cast(unsigned short, (__bf16)(o1 - (float)h1)),
                             __builtin_bit_cast(unsigned short, (__bf16)(o2 - (float)h2)),
                             __builtin_bit_cast(unsigned short, (__bf16)(o3 - (float)h3)));
  size_t idx = (size_t)node * CC + lane * 4;
  *(ushort4*)(h_hi + idx) = ohi;
  *(ushort4*)(h_lo + idx) = olo;
}

// ---------------- pool: parallel segment-sum with atomics (batch sorted) ----------------
__global__ void pool_kernel(const unsigned short* __restrict__ h_hi,
                            const unsigned short* __restrict__ h_lo,
                            const int* __restrict__ batch,
                            float* __restrict__ gpool, int N) {
  int c = threadIdx.x;
  int n0 = blockIdx.x * 64;
  int n1 = min(n0 + 64, N);
  int cur = batch[n0];
  float acc = 0.f;
  for (int n = n0; n < n1; ++n) {
    int g = batch[n];
    if (g != cur) {
      atomicAdd(&gpool[cur * CC + c], acc);
      acc = 0.f;
      cur = g;
    }
    size_t idx = (size_t)n * CC + c;
    acc += bf2f(h_hi[idx]) + bf2f(h_lo[idx]);
  }
  atomicAdd(&gpool[cur * CC + c], acc);
}

// ---------------- MLP head ----------------
__global__ void head_kernel(const float* __restrict__ gpool, const float* __restrict__ W1,
                            const float* __restrict__ b1, const float* __restrict__ W2,
                            const float* __restrict__ b2, float* __restrict__ out) {
  __shared__ float hid[64];
  int g = blockIdx.x, t = threadIdx.x;
  float acc = b1[t];
  for (int i = 0; i < CC; ++i) acc = fmaf(gpool[g * CC + i], W1[i * 64 + t], acc);
  hid[t] = fmaxf(acc, 0.f);
  __syncthreads();
  if (t < 16) {
    float o = b2[t];
    for (int i = 0; i < 64; ++i) o = fmaf(hid[i], W2[i * 16 + t], o);
    out[g * 16 + t] = o;
  }
}

extern "C" void kernel_launch(void* const* d_in, const int* in_sizes, int n_in,
                              void* d_out, int out_size, void* d_ws, size_t ws_size,
                              hipStream_t stream) {
  const float* x  = (const float*)d_in[0];
  const int* ei   = (const int*)d_in[1];
  const int* batch = (const int*)d_in[2];
  const float* Wq = (const float*)d_in[3];
  const float* bq = (const float*)d_in[4];
  const float* Wk = (const float*)d_in[5];
  const float* bk = (const float*)d_in[6];
  const float* Wv = (const float*)d_in[7];
  const float* bv = (const float*)d_in[8];
  const float* W1 = (const float*)d_in[9];
  const float* b1 = (const float*)d_in[10];
  const float* W2 = (const float*)d_in[11];
  const float* b2 = (const float*)d_in[12];
  float* out = (float*)d_out;

  int N = in_sizes[0] / CC;
  int E = in_sizes[1] / 2;
  int L = in_sizes[3] / (CC * CC);
  const int* src = ei;
  const int* dst = ei + E;

  // workspace budget: keep total < 256 MB (R3 crashed at ~278 MB)
  size_t off = 0;
  auto alloc = [&](size_t bytes) -> void* {
    void* p = (char*)d_ws + off;
    off += (bytes + 255) & ~(size_t)255;
    return p;
  };
  float* qkv = (float*)alloc((size_t)N * QKVS * 4);                   // 153.6 MB
  unsigned short* h_hi = (unsigned short*)alloc((size_t)N * CC * 2);  // 25.6 MB
  unsigned short* h_lo = (unsigned short*)alloc((size_t)N * CC * 2);  // 25.6 MB
  unsigned short* Bth = (unsigned short*)alloc((size_t)L * QKVS * CC * 2);
  unsigned short* Btl = (unsigned short*)alloc((size_t)L * QKVS * CC * 2);
  float* biascat = (float*)alloc((size_t)L * QKVS * 4);
  int* deg = (int*)alloc((size_t)N * 4);
  int* exc = (int*)alloc((size_t)N * 4);
  int* partial = (int*)alloc(SCAN_BS * 4);
  int* row_start = (int*)alloc((size_t)(N + 1) * 4);
  int* cursor = (int*)alloc((size_t)N * 4);
  int* csr_src = (int*)alloc((size_t)E * 4);
  float* gpool = (float*)alloc((size_t)NG * CC * 4);
  // total ~= 211 MB

  // CSR by dst
  hipMemsetAsync(deg, 0, (size_t)N * 4, stream);
  int eb = (E + 255) / 256;
  hist_kernel<<<eb, 256, 0, stream>>>(dst, deg, E);
  int nb = (N + SCAN_BS - 1) / SCAN_BS;
  scan1_kernel<<<nb, SCAN_BS, 0, stream>>>(deg, exc, partial, N);
  scan2_kernel<<<1, SCAN_BS, 0, stream>>>(partial, nb);
  scan3_kernel<<<(N + 1 + 255) / 256, 256, 0, stream>>>(exc, partial, row_start, cursor, N, E);
  scatter_kernel<<<eb, 256, 0, stream>>>(src, dst, cursor, csr_src, E);

  // weight prep (transpose + concat + hi/lo split)
  int wtot = L * QKVS * CC;
  wprep_kernel<<<(wtot + 255) / 256, 256, 0, stream>>>(Wq, Wk, Wv, bq, bk, bv,
                                                       Bth, Btl, biascat, L);

  // layer-0 input split
  int n4 = N * CC / 4;
  split_kernel<<<(n4 + 255) / 256, 256, 0, stream>>>(x, h_hi, h_lo, n4);

  // layers
  dim3 gemmGrid((N + 127) / 128, QKVS / 128);
  int nblocks = (N + 3) / 4;          // 4 nodes per block (wave = node)
  int npx = (nblocks + 7) / 8;        // blocks per XCD
  int ngrid = npx * 8;
  for (int l = 0; l < L; ++l) {
    qkv_gemm<<<gemmGrid, 256, 0, stream>>>(h_hi, h_lo,
                                           Bth + (size_t)l * QKVS * CC,
                                           Btl + (size_t)l * QKVS * CC,
                                           biascat + (size_t)l * QKVS, qkv, N);
    attn_fused_kernel<<<ngrid, 256, 0, stream>>>(qkv, row_start, csr_src,
                                                 h_hi, h_lo, N, npx);
  }

  // pool + head
  hipMemsetAsync(gpool, 0, (size_t)NG * CC * 4, stream);
  pool_kernel<<<(N + 63) / 64, 256, 0, stream>>>(h_hi, h_lo, batch, gpool, N);
  head_kernel<<<NG, 64, 0, stream>>>(gpool, W1, b1, W2, b2, out);
}

// Round 12
// 939.353 us; speedup vs baseline: 1.3586x; 1.3586x over previous
//
#include <hip/hip_runtime.h>
#include <math.h>

#define CC 256       // channels = HEADS * HD
#define HEADS 4
#define HD 64
#define NG 64        // num graphs
#define SCAN_BS 512
#define QKVS 768     // fused QKV output width (Q|K|V)
#define KVS 512      // packed fp16 K|V row stride
#define LDK 40       // padded LDS k-stride (bf16 elems)

typedef __attribute__((ext_vector_type(8))) short s16x8;      // 8 x bf16 (4 VGPRs)
typedef __attribute__((ext_vector_type(4))) float f32x4;
typedef __attribute__((ext_vector_type(4))) _Float16 f16x4;   // 8 B

static __device__ __forceinline__ float bf2f(unsigned short u) {
  return (float)__builtin_bit_cast(__bf16, u);
}

// ---------------- CSR build (by dst) ----------------
__global__ void hist_kernel(const int* __restrict__ dst, int* __restrict__ deg, int E) {
  int e = blockIdx.x * blockDim.x + threadIdx.x;
  if (e < E) atomicAdd(&deg[dst[e]], 1);
}

__global__ void scan1_kernel(const int* __restrict__ deg, int* __restrict__ exc,
                             int* __restrict__ partial, int n) {
  __shared__ int s[SCAN_BS];
  int t = threadIdx.x;
  int g = blockIdx.x * SCAN_BS + t;
  int v = (g < n) ? deg[g] : 0;
  s[t] = v;
  __syncthreads();
  for (int off = 1; off < SCAN_BS; off <<= 1) {
    int add = (t >= off) ? s[t - off] : 0;
    __syncthreads();
    s[t] += add;
    __syncthreads();
  }
  if (g < n) exc[g] = s[t] - v;
  if (t == SCAN_BS - 1) partial[blockIdx.x] = s[t];
}

__global__ void scan2_kernel(int* __restrict__ partial, int nb) {
  __shared__ int s[SCAN_BS];
  int t = threadIdx.x;
  int v = (t < nb) ? partial[t] : 0;
  s[t] = v;
  __syncthreads();
  for (int off = 1; off < SCAN_BS; off <<= 1) {
    int add = (t >= off) ? s[t - off] : 0;
    __syncthreads();
    s[t] += add;
    __syncthreads();
  }
  if (t < nb) partial[t] = s[t] - v;
}

__global__ void scan3_kernel(const int* __restrict__ exc, const int* __restrict__ partial,
                             int* __restrict__ row_start, int* __restrict__ cursor,
                             int n, int E) {
  int g = blockIdx.x * blockDim.x + threadIdx.x;
  if (g < n) {
    int v = exc[g] + partial[g / SCAN_BS];
    row_start[g] = v;
    cursor[g] = v;
  }
  if (g == n) row_start[n] = E;
}

__global__ void scatter_kernel(const int* __restrict__ srcArr, const int* __restrict__ dstArr,
                               int* __restrict__ cursor, int* __restrict__ csr_src, int E) {
  int e = blockIdx.x * blockDim.x + threadIdx.x;
  if (e < E) {
    int d = dstArr[e];
    int p = atomicAdd(&cursor[d], 1);
    csr_src[p] = srcArr[e];
  }
}

// ---------------- weight prep: transpose + concat + bf16 hi/lo split ----------------
__global__ void wprep_kernel(const float* __restrict__ Wq, const float* __restrict__ Wk,
                             const float* __restrict__ Wv, const float* __restrict__ bq,
                             const float* __restrict__ bk, const float* __restrict__ bv,
                             unsigned short* __restrict__ Bth, unsigned short* __restrict__ Btl,
                             float* __restrict__ biascat, int L) {
  int idx = blockIdx.x * 256 + threadIdx.x;
  int total = L * QKVS * CC;
  if (idx >= total) return;
  int k = idx & 255;
  int n = (idx >> 8) % QKVS;
  int l = idx / (QKVS * CC);
  int part = n >> 8;
  int nn = n & 255;
  const float* W = part == 0 ? Wq : (part == 1 ? Wk : Wv);
  float v = W[((long)l * CC + k) * CC + nn];
  __bf16 h = (__bf16)v;
  Bth[idx] = __builtin_bit_cast(unsigned short, h);
  Btl[idx] = __builtin_bit_cast(unsigned short, (__bf16)(v - (float)h));
  if (k == 0) {
    const float* bb = part == 0 ? bq : (part == 1 ? bk : bv);
    biascat[l * QKVS + n] = bb[l * CC + nn];
  }
}

// ---------------- activation split: fp32 -> bf16 hi + lo (layer-0 input only) ------
__global__ void split_kernel(const float* __restrict__ in, unsigned short* __restrict__ hi,
                             unsigned short* __restrict__ lo, int n4) {
  int i = blockIdx.x * 256 + threadIdx.x;
  if (i >= n4) return;
  float4 v = ((const float4*)in)[i];
  __bf16 h0 = (__bf16)v.x, h1 = (__bf16)v.y, h2 = (__bf16)v.z, h3 = (__bf16)v.w;
  ushort4 hv = make_ushort4(__builtin_bit_cast(unsigned short, h0),
                            __builtin_bit_cast(unsigned short, h1),
                            __builtin_bit_cast(unsigned short, h2),
                            __builtin_bit_cast(unsigned short, h3));
  ushort4 lv = make_ushort4(__builtin_bit_cast(unsigned short, (__bf16)(v.x - (float)h0)),
                            __builtin_bit_cast(unsigned short, (__bf16)(v.y - (float)h1)),
                            __builtin_bit_cast(unsigned short, (__bf16)(v.z - (float)h2)),
                            __builtin_bit_cast(unsigned short, (__bf16)(v.w - (float)h3)));
  ((ushort4*)hi)[i] = hv;
  ((ushort4*)lo)[i] = lv;
}

// ---------------- fused QKV GEMM via split-bf16 MFMA ----------------
// Output: Q (cols 0..255) -> fp32 Qb[N][256]; K,V (cols 256..767) -> fp16 kvh[N][512].
__global__ __launch_bounds__(256) void qkv_gemm(const unsigned short* __restrict__ Ah,
                                                const unsigned short* __restrict__ Al,
                                                const unsigned short* __restrict__ Bh,
                                                const unsigned short* __restrict__ Bl,
                                                const float* __restrict__ biascat,
                                                float* __restrict__ Qb,
                                                _Float16* __restrict__ kvh, int M) {
  __shared__ unsigned short As_h[128 * LDK], As_l[128 * LDK];
  __shared__ unsigned short Bs_h[128 * LDK], Bs_l[128 * LDK];
  int t = threadIdx.x;
  int bm = blockIdx.x, bn = blockIdx.y;
  int lane = t & 63, wave = t >> 6;
  int mo = (wave >> 1) * 64, no = (wave & 1) * 64;
  int col_l = lane & 15, q = lane >> 4;

  f32x4 acc[4][4];
#pragma unroll
  for (int i = 0; i < 4; ++i)
#pragma unroll
    for (int j = 0; j < 4; ++j) acc[i][j] = (f32x4)0.f;

  int sr = t >> 1;
  int sh = (t & 1) * 16;
  long arow = (long)bm * 128 + sr;
  bool aval = arow < M;
  const unsigned short* agh = Ah + arow * CC + sh;
  const unsigned short* agl = Al + arow * CC + sh;
  const unsigned short* bgh = Bh + ((long)bn * 128 + sr) * CC + sh;
  const unsigned short* bgl = Bl + ((long)bn * 128 + sr) * CC + sh;
  uint4 zz = make_uint4(0, 0, 0, 0);

  for (int kt = 0; kt < CC; kt += 32) {
    uint4 ah0 = zz, ah1 = zz, al0 = zz, al1 = zz;
    if (aval) {
      ah0 = *(const uint4*)(agh + kt);
      ah1 = *(const uint4*)(agh + kt + 8);
      al0 = *(const uint4*)(agl + kt);
      al1 = *(const uint4*)(agl + kt + 8);
    }
    uint4 bh0 = *(const uint4*)(bgh + kt);
    uint4 bh1 = *(const uint4*)(bgh + kt + 8);
    uint4 bl0 = *(const uint4*)(bgl + kt);
    uint4 bl1 = *(const uint4*)(bgl + kt + 8);
    __syncthreads();
    *(uint4*)&As_h[sr * LDK + sh] = ah0;
    *(uint4*)&As_h[sr * LDK + sh + 8] = ah1;
    *(uint4*)&As_l[sr * LDK + sh] = al0;
    *(uint4*)&As_l[sr * LDK + sh + 8] = al1;
    *(uint4*)&Bs_h[sr * LDK + sh] = bh0;
    *(uint4*)&Bs_h[sr * LDK + sh + 8] = bh1;
    *(uint4*)&Bs_l[sr * LDK + sh] = bl0;
    *(uint4*)&Bs_l[sr * LDK + sh + 8] = bl1;
    __syncthreads();

    s16x8 afh[4], afl[4], bfh[4], bfl[4];
#pragma unroll
    for (int i = 0; i < 4; ++i) {
      int am = mo + i * 16 + col_l;
      afh[i] = *(const s16x8*)&As_h[am * LDK + q * 8];
      afl[i] = *(const s16x8*)&As_l[am * LDK + q * 8];
      int bnn = no + i * 16 + col_l;
      bfh[i] = *(const s16x8*)&Bs_h[bnn * LDK + q * 8];
      bfl[i] = *(const s16x8*)&Bs_l[bnn * LDK + q * 8];
    }
#pragma unroll
    for (int i = 0; i < 4; ++i)
#pragma unroll
      for (int j = 0; j < 4; ++j) {
        acc[i][j] = __builtin_amdgcn_mfma_f32_16x16x32_bf16(afh[i], bfh[j], acc[i][j], 0, 0, 0);
        acc[i][j] = __builtin_amdgcn_mfma_f32_16x16x32_bf16(afh[i], bfl[j], acc[i][j], 0, 0, 0);
        acc[i][j] = __builtin_amdgcn_mfma_f32_16x16x32_bf16(afl[i], bfh[j], acc[i][j], 0, 0, 0);
      }
  }

  long rbase = (long)bm * 128 + mo;
  int cbase = bn * 128 + no;
#pragma unroll
  for (int j = 0; j < 4; ++j) {
    int col = cbase + j * 16 + col_l;
    float bias = biascat[col];
#pragma unroll
    for (int i = 0; i < 4; ++i) {
#pragma unroll
      for (int r = 0; r < 4; ++r) {
        long row = rbase + i * 16 + q * 4 + r;
        if (row < M) {
          float v = acc[i][j][r] + bias;
          if (col < CC) Qb[row * CC + col] = v;
          else kvh[row * KVS + (col - CC)] = (_Float16)v;
        }
      }
    }
  }
}

// ---------------- fused attention: wave = node, fp16 K/V gather ----------------
// block = 4 nodes (XCD-swizzled), wave owns one node end-to-end. lane =
// (head=lane>>4, dim4=lane&15); one wave computes all 4 heads per edge via a
// 4-step 16-lane dot-reduce. 8-edge chunks keep 16 gather loads in flight;
// K and V of an edge live in the same 1 KB kvh row (single cache visit).
__global__ __launch_bounds__(256) void attn_fused_kernel(const float* __restrict__ Qb,
                                                         const _Float16* __restrict__ kvh,
                                                         const int* __restrict__ row_start,
                                                         const int* __restrict__ csr_src,
                                                         unsigned short* __restrict__ h_hi,
                                                         unsigned short* __restrict__ h_lo,
                                                         int N, int npx) {
  int b = blockIdx.x;
  int nb = (b & 7) * npx + (b >> 3);
  int wave = threadIdx.x >> 6;
  int lane = threadIdx.x & 63;
  int node = nb * 4 + wave;
  if (node >= N) return;
  int s0 = row_start[node], s1 = row_start[node + 1];

  const f32x4 q4 = *(const f32x4*)(Qb + (size_t)node * CC + lane * 4);

  float m = -1e30f, z = 0.f;
  f32x4 acc = (f32x4)0.f;

  int i = s0;
  for (; i + 8 <= s1; i += 8) {
    int ix[8];
#pragma unroll
    for (int u = 0; u < 8; ++u) ix[u] = csr_src[i + u];
    f16x4 kk[8], vv[8];
#pragma unroll
    for (int u = 0; u < 8; ++u) {
      const _Float16* row = kvh + (size_t)ix[u] * KVS;
      kk[u] = *(const f16x4*)(row + lane * 4);          // K
      vv[u] = *(const f16x4*)(row + 256 + lane * 4);    // V
    }
    float lg[8];
#pragma unroll
    for (int u = 0; u < 8; ++u) {
      float d = q4.x * (float)kk[u].x + q4.y * (float)kk[u].y +
                q4.z * (float)kk[u].z + q4.w * (float)kk[u].w;
#pragma unroll
      for (int off = 1; off < 16; off <<= 1) d += __shfl_xor(d, off, 64);
      lg[u] = d * 0.125f;
    }
    float cm = lg[0];
#pragma unroll
    for (int u = 1; u < 8; ++u) cm = fmaxf(cm, lg[u]);
    float mn = fmaxf(m, cm);
    float sc = __expf(m - mn);
    z *= sc;
    acc *= sc;
    m = mn;
#pragma unroll
    for (int u = 0; u < 8; ++u) {
      float e = __expf(lg[u] - m);
      z += e;
      f32x4 vf = {(float)vv[u].x, (float)vv[u].y, (float)vv[u].z, (float)vv[u].w};
      acc += e * vf;
    }
  }
  for (; i < s1; ++i) {
    int s = csr_src[i];
    const _Float16* row = kvh + (size_t)s * KVS;
    f16x4 k4 = *(const f16x4*)(row + lane * 4);
    f16x4 v4 = *(const f16x4*)(row + 256 + lane * 4);
    float d = q4.x * (float)k4.x + q4.y * (float)k4.y +
              q4.z * (float)k4.z + q4.w * (float)k4.w;
#pragma unroll
    for (int off = 1; off < 16; off <<= 1) d += __shfl_xor(d, off, 64);
    float lgs = d * 0.125f;
    float mn = fmaxf(m, lgs);
    float sc = __expf(m - mn);
    float e = __expf(lgs - mn);
    z = z * sc + e;
    f32x4 vf = {(float)v4.x, (float)v4.y, (float)v4.z, (float)v4.w};
    acc = acc * sc + e * vf;
    m = mn;
  }

  float rz = 1.f / (z + 1e-16f);
  float o0 = fmaxf(acc.x * rz, 0.f);
  float o1 = fmaxf(acc.y * rz, 0.f);
  float o2 = fmaxf(acc.z * rz, 0.f);
  float o3 = fmaxf(acc.w * rz, 0.f);
  __bf16 h0 = (__bf16)o0, h1 = (__bf16)o1, h2 = (__bf16)o2, h3 = (__bf16)o3;
  ushort4 ohi = make_ushort4(__builtin_bit_cast(unsigned short, h0),
                             __builtin_bit_cast(unsigned short, h1),
                             __builtin_bit_cast(unsigned short, h2),
                             __builtin_bit_cast(unsigned short, h3));
  ushort4 olo = make_ushort4(__builtin_bit_cast(unsigned short, (__bf16)(o0 - (float)h0)),
                             __builtin_bit_cast(unsigned short, (__bf16)(o1 - (float)h1)),
                             __builtin_bit_cast(unsigned short, (__bf16)(o2 - (float)h2)),
                             __builtin_bit_cast(unsigned short, (__bf16)(o3 - (float)h3)));
  size_t idx = (size_t)node * CC + lane * 4;
  *(ushort4*)(h_hi + idx) = ohi;
  *(ushort4*)(h_lo + idx) = olo;
}

// ---------------- pool: parallel segment-sum with atomics (batch sorted) ----------------
__global__ void pool_kernel(const unsigned short* __restrict__ h_hi,
                            const unsigned short* __restrict__ h_lo,
                            const int* __restrict__ batch,
                            float* __restrict__ gpool, int N) {
  int c = threadIdx.x;
  int n0 = blockIdx.x * 64;
  int n1 = min(n0 + 64, N);
  int cur = batch[n0];
  float acc = 0.f;
  for (int n = n0; n < n1; ++n) {
    int g = batch[n];
    if (g != cur) {
      atomicAdd(&gpool[cur * CC + c], acc);
      acc = 0.f;
      cur = g;
    }
    size_t idx = (size_t)n * CC + c;
    acc += bf2f(h_hi[idx]) + bf2f(h_lo[idx]);
  }
  atomicAdd(&gpool[cur * CC + c], acc);
}

// ---------------- MLP head ----------------
__global__ void head_kernel(const float* __restrict__ gpool, const float* __restrict__ W1,
                            const float* __restrict__ b1, const float* __restrict__ W2,
                            const float* __restrict__ b2, float* __restrict__ out) {
  __shared__ float hid[64];
  int g = blockIdx.x, t = threadIdx.x;
  float acc = b1[t];
  for (int i = 0; i < CC; ++i) acc = fmaf(gpool[g * CC + i], W1[i * 64 + t], acc);
  hid[t] = fmaxf(acc, 0.f);
  __syncthreads();
  if (t < 16) {
    float o = b2[t];
    for (int i = 0; i < 64; ++i) o = fmaf(hid[i], W2[i * 16 + t], o);
    out[g * 16 + t] = o;
  }
}

extern "C" void kernel_launch(void* const* d_in, const int* in_sizes, int n_in,
                              void* d_out, int out_size, void* d_ws, size_t ws_size,
                              hipStream_t stream) {
  const float* x  = (const float*)d_in[0];
  const int* ei   = (const int*)d_in[1];
  const int* batch = (const int*)d_in[2];
  const float* Wq = (const float*)d_in[3];
  const float* bq = (const float*)d_in[4];
  const float* Wk = (const float*)d_in[5];
  const float* bk = (const float*)d_in[6];
  const float* Wv = (const float*)d_in[7];
  const float* bv = (const float*)d_in[8];
  const float* W1 = (const float*)d_in[9];
  const float* b1 = (const float*)d_in[10];
  const float* W2 = (const float*)d_in[11];
  const float* b2 = (const float*)d_in[12];
  float* out = (float*)d_out;

  int N = in_sizes[0] / CC;
  int E = in_sizes[1] / 2;
  int L = in_sizes[3] / (CC * CC);
  const int* src = ei;
  const int* dst = ei + E;

  // workspace budget: keep total < 256 MB (R3 crashed at ~278 MB)
  size_t off = 0;
  auto alloc = [&](size_t bytes) -> void* {
    void* p = (char*)d_ws + off;
    off += (bytes + 255) & ~(size_t)255;
    return p;
  };
  float* Qb = (float*)alloc((size_t)N * CC * 4);                      // 51.2 MB
  _Float16* kvh = (_Float16*)alloc((size_t)N * KVS * 2);              // 51.2 MB
  unsigned short* h_hi = (unsigned short*)alloc((size_t)N * CC * 2);  // 25.6 MB
  unsigned short* h_lo = (unsigned short*)alloc((size_t)N * CC * 2);  // 25.6 MB
  unsigned short* Bth = (unsigned short*)alloc((size_t)L * QKVS * CC * 2);
  unsigned short* Btl = (unsigned short*)alloc((size_t)L * QKVS * CC * 2);
  float* biascat = (float*)alloc((size_t)L * QKVS * 4);
  int* deg = (int*)alloc((size_t)N * 4);
  int* exc = (int*)alloc((size_t)N * 4);
  int* partial = (int*)alloc(SCAN_BS * 4);
  int* row_start = (int*)alloc((size_t)(N + 1) * 4);
  int* cursor = (int*)alloc((size_t)N * 4);
  int* csr_src = (int*)alloc((size_t)E * 4);
  float* gpool = (float*)alloc((size_t)NG * CC * 4);
  // total ~= 160 MB

  // CSR by dst
  hipMemsetAsync(deg, 0, (size_t)N * 4, stream);
  int eb = (E + 255) / 256;
  hist_kernel<<<eb, 256, 0, stream>>>(dst, deg, E);
  int nb = (N + SCAN_BS - 1) / SCAN_BS;
  scan1_kernel<<<nb, SCAN_BS, 0, stream>>>(deg, exc, partial, N);
  scan2_kernel<<<1, SCAN_BS, 0, stream>>>(partial, nb);
  scan3_kernel<<<(N + 1 + 255) / 256, 256, 0, stream>>>(exc, partial, row_start, cursor, N, E);
  scatter_kernel<<<eb, 256, 0, stream>>>(src, dst, cursor, csr_src, E);

  // weight prep (transpose + concat + hi/lo split)
  int wtot = L * QKVS * CC;
  wprep_kernel<<<(wtot + 255) / 256, 256, 0, stream>>>(Wq, Wk, Wv, bq, bk, bv,
                                                       Bth, Btl, biascat, L);

  // layer-0 input split
  int n4 = N * CC / 4;
  split_kernel<<<(n4 + 255) / 256, 256, 0, stream>>>(x, h_hi, h_lo, n4);

  // layers
  dim3 gemmGrid((N + 127) / 128, QKVS / 128);
  int nblocks = (N + 3) / 4;          // 4 nodes per block (wave = node)
  int npx = (nblocks + 7) / 8;        // blocks per XCD
  int ngrid = npx * 8;
  for (int l = 0; l < L; ++l) {
    qkv_gemm<<<gemmGrid, 256, 0, stream>>>(h_hi, h_lo,
                                           Bth + (size_t)l * QKVS * CC,
                                           Btl + (size_t)l * QKVS * CC,
                                           biascat + (size_t)l * QKVS, Qb, kvh, N);
    attn_fused_kernel<<<ngrid, 256, 0, stream>>>(Qb, kvh, row_start, csr_src,
                                                 h_hi, h_lo, N, npx);
  }

  // pool + head
  hipMemsetAsync(gpool, 0, (size_t)NG * CC * 4, stream);
  pool_kernel<<<(N + 63) / 64, 256, 0, stream>>>(h_hi, h_lo, batch, gpool, N);
  head_kernel<<<NG, 64, 0, stream>>>(gpool, W1, b1, W2, b2, out);
}

// Round 13
// 876.524 us; speedup vs baseline: 1.4560x; 1.0717x over previous
//
#include <hip/hip_runtime.h>
#include <math.h>

#define CC 256       // channels = HEADS * HD
#define HEADS 4
#define HD 64
#define NG 64        // num graphs
#define SCAN_BS 512
#define QKVS 768     // fused QKV output width (Q|K|V)
#define KVS 512      // packed fp16 K|V row stride
#define LDK 40       // padded LDS k-stride (bf16 elems)

typedef __attribute__((ext_vector_type(8))) short s16x8;      // 8 x bf16 (4 VGPRs)
typedef __attribute__((ext_vector_type(4))) float f32x4;
typedef __attribute__((ext_vector_type(4))) _Float16 f16x4;   // 8 B

static __device__ __forceinline__ float bf2f(unsigned short u) {
  return (float)__builtin_bit_cast(__bf16, u);
}

// ---------------- CSR build (by dst) ----------------
__global__ void hist_kernel(const int* __restrict__ dst, int* __restrict__ deg, int E) {
  int e = blockIdx.x * blockDim.x + threadIdx.x;
  if (e < E) atomicAdd(&deg[dst[e]], 1);
}

__global__ void scan1_kernel(const int* __restrict__ deg, int* __restrict__ exc,
                             int* __restrict__ partial, int n) {
  __shared__ int s[SCAN_BS];
  int t = threadIdx.x;
  int g = blockIdx.x * SCAN_BS + t;
  int v = (g < n) ? deg[g] : 0;
  s[t] = v;
  __syncthreads();
  for (int off = 1; off < SCAN_BS; off <<= 1) {
    int add = (t >= off) ? s[t - off] : 0;
    __syncthreads();
    s[t] += add;
    __syncthreads();
  }
  if (g < n) exc[g] = s[t] - v;
  if (t == SCAN_BS - 1) partial[blockIdx.x] = s[t];
}

__global__ void scan2_kernel(int* __restrict__ partial, int nb) {
  __shared__ int s[SCAN_BS];
  int t = threadIdx.x;
  int v = (t < nb) ? partial[t] : 0;
  s[t] = v;
  __syncthreads();
  for (int off = 1; off < SCAN_BS; off <<= 1) {
    int add = (t >= off) ? s[t - off] : 0;
    __syncthreads();
    s[t] += add;
    __syncthreads();
  }
  if (t < nb) partial[t] = s[t] - v;
}

__global__ void scan3_kernel(const int* __restrict__ exc, const int* __restrict__ partial,
                             int* __restrict__ row_start, int* __restrict__ cursor,
                             int n, int E) {
  int g = blockIdx.x * blockDim.x + threadIdx.x;
  if (g < n) {
    int v = exc[g] + partial[g / SCAN_BS];
    row_start[g] = v;
    cursor[g] = v;
  }
  if (g == n) row_start[n] = E;
}

__global__ void scatter_kernel(const int* __restrict__ srcArr, const int* __restrict__ dstArr,
                               int* __restrict__ cursor, int* __restrict__ csr_src, int E) {
  int e = blockIdx.x * blockDim.x + threadIdx.x;
  if (e < E) {
    int d = dstArr[e];
    int p = atomicAdd(&cursor[d], 1);
    csr_src[p] = srcArr[e];
  }
}

// ---------------- weight prep: transpose + concat + bf16 hi/lo split ----------------
__global__ void wprep_kernel(const float* __restrict__ Wq, const float* __restrict__ Wk,
                             const float* __restrict__ Wv, const float* __restrict__ bq,
                             const float* __restrict__ bk, const float* __restrict__ bv,
                             unsigned short* __restrict__ Bth, unsigned short* __restrict__ Btl,
                             float* __restrict__ biascat, int L) {
  int idx = blockIdx.x * 256 + threadIdx.x;
  int total = L * QKVS * CC;
  if (idx >= total) return;
  int k = idx & 255;
  int n = (idx >> 8) % QKVS;
  int l = idx / (QKVS * CC);
  int part = n >> 8;
  int nn = n & 255;
  const float* W = part == 0 ? Wq : (part == 1 ? Wk : Wv);
  float v = W[((long)l * CC + k) * CC + nn];
  __bf16 h = (__bf16)v;
  Bth[idx] = __builtin_bit_cast(unsigned short, h);
  Btl[idx] = __builtin_bit_cast(unsigned short, (__bf16)(v - (float)h));
  if (k == 0) {
    const float* bb = part == 0 ? bq : (part == 1 ? bk : bv);
    biascat[l * QKVS + n] = bb[l * CC + nn];
  }
}

// ---------------- activation split: fp32 -> bf16 hi + lo (layer-0 input only) ------
__global__ void split_kernel(const float* __restrict__ in, unsigned short* __restrict__ hi,
                             unsigned short* __restrict__ lo, int n4) {
  int i = blockIdx.x * 256 + threadIdx.x;
  if (i >= n4) return;
  float4 v = ((const float4*)in)[i];
  __bf16 h0 = (__bf16)v.x, h1 = (__bf16)v.y, h2 = (__bf16)v.z, h3 = (__bf16)v.w;
  ushort4 hv = make_ushort4(__builtin_bit_cast(unsigned short, h0),
                            __builtin_bit_cast(unsigned short, h1),
                            __builtin_bit_cast(unsigned short, h2),
                            __builtin_bit_cast(unsigned short, h3));
  ushort4 lv = make_ushort4(__builtin_bit_cast(unsigned short, (__bf16)(v.x - (float)h0)),
                            __builtin_bit_cast(unsigned short, (__bf16)(v.y - (float)h1)),
                            __builtin_bit_cast(unsigned short, (__bf16)(v.z - (float)h2)),
                            __builtin_bit_cast(unsigned short, (__bf16)(v.w - (float)h3)));
  ((ushort4*)hi)[i] = hv;
  ((ushort4*)lo)[i] = lv;
}

// ---------------- fused QKV GEMM via split-bf16 MFMA ----------------
// Grid (6, nmb): bn = blockIdx.x (FAST: 6 blocks sharing one A-tile dispatch
// back-to-back -> A fetched from HBM once, not once per column group).
// bn<2 -> Q block (fp32 out, 64B segments); bn>=2 -> K/V block (fp16 out,
// staged through LDS for full-128B-row coalesced writes).
__global__ __launch_bounds__(256) void qkv_gemm(const unsigned short* __restrict__ Ah,
                                                const unsigned short* __restrict__ Al,
                                                const unsigned short* __restrict__ Bh,
                                                const unsigned short* __restrict__ Bl,
                                                const float* __restrict__ biascat,
                                                float* __restrict__ Qb,
                                                _Float16* __restrict__ kvh, int M) {
  __shared__ unsigned short S[4 * 128 * LDK];       // As_h | As_l | Bs_h | Bs_l (40960 B)
  unsigned short* As_h = S;
  unsigned short* As_l = S + 128 * LDK;
  unsigned short* Bs_h = S + 2 * 128 * LDK;
  unsigned short* Bs_l = S + 3 * 128 * LDK;
  int t = threadIdx.x;
  int bn = blockIdx.x, bm = blockIdx.y;
  int lane = t & 63, wave = t >> 6;
  int mo = (wave >> 1) * 64, no = (wave & 1) * 64;
  int col_l = lane & 15, q = lane >> 4;

  f32x4 acc[4][4];
#pragma unroll
  for (int i = 0; i < 4; ++i)
#pragma unroll
    for (int j = 0; j < 4; ++j) acc[i][j] = (f32x4)0.f;

  int sr = t >> 1;
  int sh = (t & 1) * 16;
  long arow = (long)bm * 128 + sr;
  bool aval = arow < M;
  const unsigned short* agh = Ah + arow * CC + sh;
  const unsigned short* agl = Al + arow * CC + sh;
  const unsigned short* bgh = Bh + ((long)bn * 128 + sr) * CC + sh;
  const unsigned short* bgl = Bl + ((long)bn * 128 + sr) * CC + sh;
  uint4 zz = make_uint4(0, 0, 0, 0);

  for (int kt = 0; kt < CC; kt += 32) {
    uint4 ah0 = zz, ah1 = zz, al0 = zz, al1 = zz;
    if (aval) {
      ah0 = *(const uint4*)(agh + kt);
      ah1 = *(const uint4*)(agh + kt + 8);
      al0 = *(const uint4*)(agl + kt);
      al1 = *(const uint4*)(agl + kt + 8);
    }
    uint4 bh0 = *(const uint4*)(bgh + kt);
    uint4 bh1 = *(const uint4*)(bgh + kt + 8);
    uint4 bl0 = *(const uint4*)(bgl + kt);
    uint4 bl1 = *(const uint4*)(bgl + kt + 8);
    __syncthreads();
    *(uint4*)&As_h[sr * LDK + sh] = ah0;
    *(uint4*)&As_h[sr * LDK + sh + 8] = ah1;
    *(uint4*)&As_l[sr * LDK + sh] = al0;
    *(uint4*)&As_l[sr * LDK + sh + 8] = al1;
    *(uint4*)&Bs_h[sr * LDK + sh] = bh0;
    *(uint4*)&Bs_h[sr * LDK + sh + 8] = bh1;
    *(uint4*)&Bs_l[sr * LDK + sh] = bl0;
    *(uint4*)&Bs_l[sr * LDK + sh + 8] = bl1;
    __syncthreads();

    s16x8 afh[4], afl[4], bfh[4], bfl[4];
#pragma unroll
    for (int i = 0; i < 4; ++i) {
      int am = mo + i * 16 + col_l;
      afh[i] = *(const s16x8*)&As_h[am * LDK + q * 8];
      afl[i] = *(const s16x8*)&As_l[am * LDK + q * 8];
      int bnn = no + i * 16 + col_l;
      bfh[i] = *(const s16x8*)&Bs_h[bnn * LDK + q * 8];
      bfl[i] = *(const s16x8*)&Bs_l[bnn * LDK + q * 8];
    }
#pragma unroll
    for (int i = 0; i < 4; ++i)
#pragma unroll
      for (int j = 0; j < 4; ++j) {
        acc[i][j] = __builtin_amdgcn_mfma_f32_16x16x32_bf16(afh[i], bfh[j], acc[i][j], 0, 0, 0);
        acc[i][j] = __builtin_amdgcn_mfma_f32_16x16x32_bf16(afh[i], bfl[j], acc[i][j], 0, 0, 0);
        acc[i][j] = __builtin_amdgcn_mfma_f32_16x16x32_bf16(afl[i], bfh[j], acc[i][j], 0, 0, 0);
      }
  }

  long rbase = (long)bm * 128 + mo;
  int cbase = bn * 128 + no;
  if (bn < 2) {
    // Q block: direct fp32 stores (16 consecutive lanes -> 64 B = one line)
#pragma unroll
    for (int j = 0; j < 4; ++j) {
      int col = cbase + j * 16 + col_l;
      float bias = biascat[col];
#pragma unroll
      for (int i = 0; i < 4; ++i) {
#pragma unroll
        for (int r = 0; r < 4; ++r) {
          long row = rbase + i * 16 + q * 4 + r;
          if (row < M) Qb[row * CC + col] = acc[i][j][r] + bias;
        }
      }
    }
  } else {
    // KV block: stage fp16 tile in LDS (stride 68: u16 writes 2-way = free),
    // then read back rows and store full 128 B segments.
    __syncthreads();                       // bn uniform per block: all waves reach this
    unsigned short* T = S + wave * 4352;   // 64 x 68 fp16 per wave (8704 B)
#pragma unroll
    for (int j = 0; j < 4; ++j) {
      int col = cbase + j * 16 + col_l;
      float bias = biascat[col];
      int cl = j * 16 + col_l;
#pragma unroll
      for (int i = 0; i < 4; ++i) {
#pragma unroll
        for (int r = 0; r < 4; ++r) {
          int rl = i * 16 + q * 4 + r;
          T[rl * 68 + cl] =
              __builtin_bit_cast(unsigned short, (_Float16)(acc[i][j][r] + bias));
        }
      }
    }
    // wave-local readback (compiler inserts lgkmcnt waits)
    int kvcol = cbase - CC + (lane & 15) * 4;    // 4 fp16 per lane
#pragma unroll
    for (int p = 0; p < 16; ++p) {
      int rl = p * 4 + (lane >> 4);
      uint2 v = *(const uint2*)&T[rl * 68 + (lane & 15) * 4];
      long row = rbase + rl;
      if (row < M) *(uint2*)(kvh + row * KVS + kvcol) = v;
    }
  }
}

// ---------------- fused attention: wave = node, fp16 K/V gather ----------------
// block = 4 nodes (XCD-swizzled), wave owns one node end-to-end. lane =
// (head=lane>>4, dim4=lane&15); one wave computes all 4 heads per edge via a
// 4-step 16-lane dot-reduce. 8-edge chunks keep 16 gather loads in flight;
// K and V of an edge live in the same 1 KB kvh row (single cache visit).
__global__ __launch_bounds__(256) void attn_fused_kernel(const float* __restrict__ Qb,
                                                         const _Float16* __restrict__ kvh,
                                                         const int* __restrict__ row_start,
                                                         const int* __restrict__ csr_src,
                                                         unsigned short* __restrict__ h_hi,
                                                         unsigned short* __restrict__ h_lo,
                                                         int N, int npx) {
  int b = blockIdx.x;
  int nb = (b & 7) * npx + (b >> 3);
  int wave = threadIdx.x >> 6;
  int lane = threadIdx.x & 63;
  int node = nb * 4 + wave;
  if (node >= N) return;
  int s0 = row_start[node], s1 = row_start[node + 1];

  const f32x4 q4 = *(const f32x4*)(Qb + (size_t)node * CC + lane * 4);

  float m = -1e30f, z = 0.f;
  f32x4 acc = (f32x4)0.f;

  int i = s0;
  for (; i + 8 <= s1; i += 8) {
    int ix[8];
#pragma unroll
    for (int u = 0; u < 8; ++u) ix[u] = csr_src[i + u];
    f16x4 kk[8], vv[8];
#pragma unroll
    for (int u = 0; u < 8; ++u) {
      const _Float16* row = kvh + (size_t)ix[u] * KVS;
      kk[u] = *(const f16x4*)(row + lane * 4);          // K
      vv[u] = *(const f16x4*)(row + 256 + lane * 4);    // V
    }
    float lg[8];
#pragma unroll
    for (int u = 0; u < 8; ++u) {
      float d = q4.x * (float)kk[u].x + q4.y * (float)kk[u].y +
                q4.z * (float)kk[u].z + q4.w * (float)kk[u].w;
#pragma unroll
      for (int off = 1; off < 16; off <<= 1) d += __shfl_xor(d, off, 64);
      lg[u] = d * 0.125f;
    }
    float cm = lg[0];
#pragma unroll
    for (int u = 1; u < 8; ++u) cm = fmaxf(cm, lg[u]);
    float mn = fmaxf(m, cm);
    float sc = __expf(m - mn);
    z *= sc;
    acc *= sc;
    m = mn;
#pragma unroll
    for (int u = 0; u < 8; ++u) {
      float e = __expf(lg[u] - m);
      z += e;
      f32x4 vf = {(float)vv[u].x, (float)vv[u].y, (float)vv[u].z, (float)vv[u].w};
      acc += e * vf;
    }
  }
  for (; i < s1; ++i) {
    int s = csr_src[i];
    const _Float16* row = kvh + (size_t)s * KVS;
    f16x4 k4 = *(const f16x4*)(row + lane * 4);
    f16x4 v4 = *(const f16x4*)(row + 256 + lane * 4);
    float d = q4.x * (float)k4.x + q4.y * (float)k4.y +
              q4.z * (float)k4.z + q4.w * (float)k4.w;
#pragma unroll
    for (int off = 1; off < 16; off <<= 1) d += __shfl_xor(d, off, 64);
    float lgs = d * 0.125f;
    float mn = fmaxf(m, lgs);
    float sc = __expf(m - mn);
    float e = __expf(lgs - mn);
    z = z * sc + e;
    f32x4 vf = {(float)v4.x, (float)v4.y, (float)v4.z, (float)v4.w};
    acc = acc * sc + e * vf;
    m = mn;
  }

  float rz = 1.f / (z + 1e-16f);
  float o0 = fmaxf(acc.x * rz, 0.f);
  float o1 = fmaxf(acc.y * rz, 0.f);
  float o2 = fmaxf(acc.z * rz, 0.f);
  float o3 = fmaxf(acc.w * rz, 0.f);
  __bf16 h0 = (__bf16)o0, h1 = (__bf16)o1, h2 = (__bf16)o2, h3 = (__bf16)o3;
  ushort4 ohi = make_ushort4(__builtin_bit_cast(unsigned short, h0),
                             __builtin_bit_cast(unsigned short, h1),
                             __builtin_bit_cast(unsigned short, h2),
                             __builtin_bit_cast(unsigned short, h3));
  ushort4 olo = make_ushort4(__builtin_bit_cast(unsigned short, (__bf16)(o0 - (float)h0)),
                             __builtin_bit_cast(unsigned short, (__bf16)(o1 - (float)h1)),
                             __builtin_bit_cast(unsigned short, (__bf16)(o2 - (float)h2)),
                             __builtin_bit_cast(unsigned short, (__bf16)(o3 - (float)h3)));
  size_t idx = (size_t)node * CC + lane * 4;
  *(ushort4*)(h_hi + idx) = ohi;
  *(ushort4*)(h_lo + idx) = olo;
}

// ---------------- pool: parallel segment-sum with atomics (batch sorted) ----------------
__global__ void pool_kernel(const unsigned short* __restrict__ h_hi,
                            const unsigned short* __restrict__ h_lo,
                            const int* __restrict__ batch,
                            float* __restrict__ gpool, int N) {
  int c = threadIdx.x;
  int n0 = blockIdx.x * 64;
  int n1 = min(n0 + 64, N);
  int cur = batch[n0];
  float acc = 0.f;
  for (int n = n0; n < n1; ++n) {
    int g = batch[n];
    if (g != cur) {
      atomicAdd(&gpool[cur * CC + c], acc);
      acc = 0.f;
      cur = g;
    }
    size_t idx = (size_t)n * CC + c;
    acc += bf2f(h_hi[idx]) + bf2f(h_lo[idx]);
  }
  atomicAdd(&gpool[cur * CC + c], acc);
}

// ---------------- MLP head ----------------
__global__ void head_kernel(const float* __restrict__ gpool, const float* __restrict__ W1,
                            const float* __restrict__ b1, const float* __restrict__ W2,
                            const float* __restrict__ b2, float* __restrict__ out) {
  __shared__ float hid[64];
  int g = blockIdx.x, t = threadIdx.x;
  float acc = b1[t];
  for (int i = 0; i < CC; ++i) acc = fmaf(gpool[g * CC + i], W1[i * 64 + t], acc);
  hid[t] = fmaxf(acc, 0.f);
  __syncthreads();
  if (t < 16) {
    float o = b2[t];
    for (int i = 0; i < 64; ++i) o = fmaf(hid[i], W2[i * 16 + t], o);
    out[g * 16 + t] = o;
  }
}

extern "C" void kernel_launch(void* const* d_in, const int* in_sizes, int n_in,
                              void* d_out, int out_size, void* d_ws, size_t ws_size,
                              hipStream_t stream) {
  const float* x  = (const float*)d_in[0];
  const int* ei   = (const int*)d_in[1];
  const int* batch = (const int*)d_in[2];
  const float* Wq = (const float*)d_in[3];
  const float* bq = (const float*)d_in[4];
  const float* Wk = (const float*)d_in[5];
  const float* bk = (const float*)d_in[6];
  const float* Wv = (const float*)d_in[7];
  const float* bv = (const float*)d_in[8];
  const float* W1 = (const float*)d_in[9];
  const float* b1 = (const float*)d_in[10];
  const float* W2 = (const float*)d_in[11];
  const float* b2 = (const float*)d_in[12];
  float* out = (float*)d_out;

  int N = in_sizes[0] / CC;
  int E = in_sizes[1] / 2;
  int L = in_sizes[3] / (CC * CC);
  const int* src = ei;
  const int* dst = ei + E;

  // workspace budget: keep total < 256 MB (R3 crashed at ~278 MB)
  size_t off = 0;
  auto alloc = [&](size_t bytes) -> void* {
    void* p = (char*)d_ws + off;
    off += (bytes + 255) & ~(size_t)255;
    return p;
  };
  float* Qb = (float*)alloc((size_t)N * CC * 4);                      // 51.2 MB
  _Float16* kvh = (_Float16*)alloc((size_t)N * KVS * 2);              // 51.2 MB
  unsigned short* h_hi = (unsigned short*)alloc((size_t)N * CC * 2);  // 25.6 MB
  unsigned short* h_lo = (unsigned short*)alloc((size_t)N * CC * 2);  // 25.6 MB
  unsigned short* Bth = (unsigned short*)alloc((size_t)L * QKVS * CC * 2);
  unsigned short* Btl = (unsigned short*)alloc((size_t)L * QKVS * CC * 2);
  float* biascat = (float*)alloc((size_t)L * QKVS * 4);
  int* deg = (int*)alloc((size_t)N * 4);
  int* exc = (int*)alloc((size_t)N * 4);
  int* partial = (int*)alloc(SCAN_BS * 4);
  int* row_start = (int*)alloc((size_t)(N + 1) * 4);
  int* cursor = (int*)alloc((size_t)N * 4);
  int* csr_src = (int*)alloc((size_t)E * 4);
  float* gpool = (float*)alloc((size_t)NG * CC * 4);
  // total ~= 160 MB

  // CSR by dst
  hipMemsetAsync(deg, 0, (size_t)N * 4, stream);
  int eb = (E + 255) / 256;
  hist_kernel<<<eb, 256, 0, stream>>>(dst, deg, E);
  int nb = (N + SCAN_BS - 1) / SCAN_BS;
  scan1_kernel<<<nb, SCAN_BS, 0, stream>>>(deg, exc, partial, N);
  scan2_kernel<<<1, SCAN_BS, 0, stream>>>(partial, nb);
  scan3_kernel<<<(N + 1 + 255) / 256, 256, 0, stream>>>(exc, partial, row_start, cursor, N, E);
  scatter_kernel<<<eb, 256, 0, stream>>>(src, dst, cursor, csr_src, E);

  // weight prep (transpose + concat + hi/lo split)
  int wtot = L * QKVS * CC;
  wprep_kernel<<<(wtot + 255) / 256, 256, 0, stream>>>(Wq, Wk, Wv, bq, bk, bv,
                                                       Bth, Btl, biascat, L);

  // layer-0 input split
  int n4 = N * CC / 4;
  split_kernel<<<(n4 + 255) / 256, 256, 0, stream>>>(x, h_hi, h_lo, n4);

  // layers
  dim3 gemmGrid(QKVS / 128, (N + 127) / 128);   // bn FAST -> A-tile reuse
  int nblocks = (N + 3) / 4;          // 4 nodes per block (wave = node)
  int npx = (nblocks + 7) / 8;        // blocks per XCD
  int ngrid = npx * 8;
  for (int l = 0; l < L; ++l) {
    qkv_gemm<<<gemmGrid, 256, 0, stream>>>(h_hi, h_lo,
                                           Bth + (size_t)l * QKVS * CC,
                                           Btl + (size_t)l * QKVS * CC,
                                           biascat + (size_t)l * QKVS, Qb, kvh, N);
    attn_fused_kernel<<<ngrid, 256, 0, stream>>>(Qb, kvh, row_start, csr_src,
                                                 h_hi, h_lo, N, npx);
  }

  // pool + head
  hipMemsetAsync(gpool, 0, (size_t)NG * CC * 4, stream);
  pool_kernel<<<(N + 63) / 64, 256, 0, stream>>>(h_hi, h_lo, batch, gpool, N);
  head_kernel<<<NG, 64, 0, stream>>>(gpool, W1, b1, W2, b2, out);
}

// Round 14
// 855.995 us; speedup vs baseline: 1.4909x; 1.0240x over previous
//
#include <hip/hip_runtime.h>
#include <math.h>

#define CC 256       // channels = HEADS * HD
#define HEADS 4
#define HD 64
#define NG 64        // num graphs
#define SCAN_BS 512
#define QKVS 768     // fused QKV output width (Q|K|V)
#define KVS 512      // packed fp16 K|V row stride
#define LDK 40       // padded LDS k-stride (bf16 elems)

typedef __attribute__((ext_vector_type(8))) short s16x8;      // 8 x bf16 (4 VGPRs)
typedef __attribute__((ext_vector_type(4))) float f32x4;
typedef __attribute__((ext_vector_type(4))) _Float16 f16x4;   // 8 B
typedef __attribute__((ext_vector_type(2))) _Float16 f16x2;

static __device__ __forceinline__ float bf2f(unsigned short u) {
  return (float)__builtin_bit_cast(__bf16, u);
}

#if __has_builtin(__builtin_amdgcn_fdot2)
static __device__ __forceinline__ float qkdot(f16x2 q0, f16x2 q1, f16x4 k) {
  f16x2 k0 = {k.x, k.y}, k1 = {k.z, k.w};
  return __builtin_amdgcn_fdot2(q0, k0, __builtin_amdgcn_fdot2(q1, k1, 0.f, false), false);
}
#else
static __device__ __forceinline__ float qkdot(f16x2 q0, f16x2 q1, f16x4 k) {
  return (float)q0.x * (float)k.x + (float)q0.y * (float)k.y +
         (float)q1.x * (float)k.z + (float)q1.y * (float)k.w;
}
#endif

// ---------------- fused prologue: hist | wprep | split (independent jobs) ----------
__global__ void prep_kernel(const int* __restrict__ dst, int* __restrict__ deg, int E,
                            const float* __restrict__ Wq, const float* __restrict__ Wk,
                            const float* __restrict__ Wv, const float* __restrict__ bq,
                            const float* __restrict__ bk, const float* __restrict__ bv,
                            unsigned short* __restrict__ Bth, unsigned short* __restrict__ Btl,
                            float* __restrict__ biascat, int L,
                            const float* __restrict__ x, unsigned short* __restrict__ hi,
                            unsigned short* __restrict__ lo, int n4,
                            int nbh, int nbw) {
  int b = blockIdx.x;
  if (b < nbh) {
    int e = b * 256 + threadIdx.x;
    if (e < E) atomicAdd(&deg[dst[e]], 1);
    return;
  }
  b -= nbh;
  if (b < nbw) {
    int idx = b * 256 + threadIdx.x;
    int total = L * QKVS * CC;
    if (idx >= total) return;
    int k = idx & 255;
    int n = (idx >> 8) % QKVS;
    int l = idx / (QKVS * CC);
    int part = n >> 8;
    int nn = n & 255;
    const float* W = part == 0 ? Wq : (part == 1 ? Wk : Wv);
    float v = W[((long)l * CC + k) * CC + nn];
    __bf16 h = (__bf16)v;
    Bth[idx] = __builtin_bit_cast(unsigned short, h);
    Btl[idx] = __builtin_bit_cast(unsigned short, (__bf16)(v - (float)h));
    if (k == 0) {
      const float* bb = part == 0 ? bq : (part == 1 ? bk : bv);
      biascat[l * QKVS + n] = bb[l * CC + nn];
    }
    return;
  }
  b -= nbw;
  int i = b * 256 + threadIdx.x;
  if (i >= n4) return;
  float4 v = ((const float4*)x)[i];
  __bf16 h0 = (__bf16)v.x, h1 = (__bf16)v.y, h2 = (__bf16)v.z, h3 = (__bf16)v.w;
  ushort4 hv = make_ushort4(__builtin_bit_cast(unsigned short, h0),
                            __builtin_bit_cast(unsigned short, h1),
                            __builtin_bit_cast(unsigned short, h2),
                            __builtin_bit_cast(unsigned short, h3));
  ushort4 lv = make_ushort4(__builtin_bit_cast(unsigned short, (__bf16)(v.x - (float)h0)),
                            __builtin_bit_cast(unsigned short, (__bf16)(v.y - (float)h1)),
                            __builtin_bit_cast(unsigned short, (__bf16)(v.z - (float)h2)),
                            __builtin_bit_cast(unsigned short, (__bf16)(v.w - (float)h3)));
  ((ushort4*)hi)[i] = hv;
  ((ushort4*)lo)[i] = lv;
}

// ---------------- CSR scan chain ----------------
__global__ void scan1_kernel(const int* __restrict__ deg, int* __restrict__ exc,
                             int* __restrict__ partial, int n) {
  __shared__ int s[SCAN_BS];
  int t = threadIdx.x;
  int g = blockIdx.x * SCAN_BS + t;
  int v = (g < n) ? deg[g] : 0;
  s[t] = v;
  __syncthreads();
  for (int off = 1; off < SCAN_BS; off <<= 1) {
    int add = (t >= off) ? s[t - off] : 0;
    __syncthreads();
    s[t] += add;
    __syncthreads();
  }
  if (g < n) exc[g] = s[t] - v;
  if (t == SCAN_BS - 1) partial[blockIdx.x] = s[t];
}

__global__ void scan2_kernel(int* __restrict__ partial, int nb) {
  __shared__ int s[SCAN_BS];
  int t = threadIdx.x;
  int v = (t < nb) ? partial[t] : 0;
  s[t] = v;
  __syncthreads();
  for (int off = 1; off < SCAN_BS; off <<= 1) {
    int add = (t >= off) ? s[t - off] : 0;
    __syncthreads();
    s[t] += add;
    __syncthreads();
  }
  if (t < nb) partial[t] = s[t] - v;
}

__global__ void scan3_kernel(const int* __restrict__ exc, const int* __restrict__ partial,
                             int* __restrict__ row_start, int* __restrict__ cursor,
                             int n, int E) {
  int g = blockIdx.x * blockDim.x + threadIdx.x;
  if (g < n) {
    int v = exc[g] + partial[g / SCAN_BS];
    row_start[g] = v;
    cursor[g] = v;
  }
  if (g == n) row_start[n] = E;
}

__global__ void scatter_kernel(const int* __restrict__ srcArr, const int* __restrict__ dstArr,
                               int* __restrict__ cursor, int* __restrict__ csr_src, int E) {
  int e = blockIdx.x * blockDim.x + threadIdx.x;
  if (e < E) {
    int d = dstArr[e];
    int p = atomicAdd(&cursor[d], 1);
    csr_src[p] = srcArr[e];
  }
}

// ---------------- fused QKV GEMM via split-bf16 MFMA ----------------
// Grid (6, nmb): bn = blockIdx.x (FAST: 6 blocks sharing one A-tile dispatch
// back-to-back -> A fetched from HBM once). bn<2 -> Q block (fp32 out);
// bn>=2 -> K/V block (fp16 out, LDS-staged for full-128B coalesced writes).
__global__ __launch_bounds__(256) void qkv_gemm(const unsigned short* __restrict__ Ah,
                                                const unsigned short* __restrict__ Al,
                                                const unsigned short* __restrict__ Bh,
                                                const unsigned short* __restrict__ Bl,
                                                const float* __restrict__ biascat,
                                                float* __restrict__ Qb,
                                                _Float16* __restrict__ kvh, int M) {
  __shared__ unsigned short S[4 * 128 * LDK];       // As_h | As_l | Bs_h | Bs_l (40960 B)
  unsigned short* As_h = S;
  unsigned short* As_l = S + 128 * LDK;
  unsigned short* Bs_h = S + 2 * 128 * LDK;
  unsigned short* Bs_l = S + 3 * 128 * LDK;
  int t = threadIdx.x;
  int bn = blockIdx.x, bm = blockIdx.y;
  int lane = t & 63, wave = t >> 6;
  int mo = (wave >> 1) * 64, no = (wave & 1) * 64;
  int col_l = lane & 15, q = lane >> 4;

  f32x4 acc[4][4];
#pragma unroll
  for (int i = 0; i < 4; ++i)
#pragma unroll
    for (int j = 0; j < 4; ++j) acc[i][j] = (f32x4)0.f;

  int sr = t >> 1;
  int sh = (t & 1) * 16;
  long arow = (long)bm * 128 + sr;
  bool aval = arow < M;
  const unsigned short* agh = Ah + arow * CC + sh;
  const unsigned short* agl = Al + arow * CC + sh;
  const unsigned short* bgh = Bh + ((long)bn * 128 + sr) * CC + sh;
  const unsigned short* bgl = Bl + ((long)bn * 128 + sr) * CC + sh;
  uint4 zz = make_uint4(0, 0, 0, 0);

  for (int kt = 0; kt < CC; kt += 32) {
    uint4 ah0 = zz, ah1 = zz, al0 = zz, al1 = zz;
    if (aval) {
      ah0 = *(const uint4*)(agh + kt);
      ah1 = *(const uint4*)(agh + kt + 8);
      al0 = *(const uint4*)(agl + kt);
      al1 = *(const uint4*)(agl + kt + 8);
    }
    uint4 bh0 = *(const uint4*)(bgh + kt);
    uint4 bh1 = *(const uint4*)(bgh + kt + 8);
    uint4 bl0 = *(const uint4*)(bgl + kt);
    uint4 bl1 = *(const uint4*)(bgl + kt + 8);
    __syncthreads();
    *(uint4*)&As_h[sr * LDK + sh] = ah0;
    *(uint4*)&As_h[sr * LDK + sh + 8] = ah1;
    *(uint4*)&As_l[sr * LDK + sh] = al0;
    *(uint4*)&As_l[sr * LDK + sh + 8] = al1;
    *(uint4*)&Bs_h[sr * LDK + sh] = bh0;
    *(uint4*)&Bs_h[sr * LDK + sh + 8] = bh1;
    *(uint4*)&Bs_l[sr * LDK + sh] = bl0;
    *(uint4*)&Bs_l[sr * LDK + sh + 8] = bl1;
    __syncthreads();

    s16x8 afh[4], afl[4], bfh[4], bfl[4];
#pragma unroll
    for (int i = 0; i < 4; ++i) {
      int am = mo + i * 16 + col_l;
      afh[i] = *(const s16x8*)&As_h[am * LDK + q * 8];
      afl[i] = *(const s16x8*)&As_l[am * LDK + q * 8];
      int bnn = no + i * 16 + col_l;
      bfh[i] = *(const s16x8*)&Bs_h[bnn * LDK + q * 8];
      bfl[i] = *(const s16x8*)&Bs_l[bnn * LDK + q * 8];
    }
#pragma unroll
    for (int i = 0; i < 4; ++i)
#pragma unroll
      for (int j = 0; j < 4; ++j) {
        acc[i][j] = __builtin_amdgcn_mfma_f32_16x16x32_bf16(afh[i], bfh[j], acc[i][j], 0, 0, 0);
        acc[i][j] = __builtin_amdgcn_mfma_f32_16x16x32_bf16(afh[i], bfl[j], acc[i][j], 0, 0, 0);
        acc[i][j] = __builtin_amdgcn_mfma_f32_16x16x32_bf16(afl[i], bfh[j], acc[i][j], 0, 0, 0);
      }
  }

  long rbase = (long)bm * 128 + mo;
  int cbase = bn * 128 + no;
  if (bn < 2) {
    // Q block: direct fp32 stores (16 consecutive lanes -> 64 B = one line)
#pragma unroll
    for (int j = 0; j < 4; ++j) {
      int col = cbase + j * 16 + col_l;
      float bias = biascat[col];
#pragma unroll
      for (int i = 0; i < 4; ++i) {
#pragma unroll
        for (int r = 0; r < 4; ++r) {
          long row = rbase + i * 16 + q * 4 + r;
          if (row < M) Qb[row * CC + col] = acc[i][j][r] + bias;
        }
      }
    }
  } else {
    // KV block: stage fp16 tile in LDS (stride 68), then coalesced 128B rows.
    __syncthreads();                       // bn uniform per block
    unsigned short* T = S + wave * 4352;   // 64 x 68 fp16 per wave
#pragma unroll
    for (int j = 0; j < 4; ++j) {
      int col = cbase + j * 16 + col_l;
      float bias = biascat[col];
      int cl = j * 16 + col_l;
#pragma unroll
      for (int i = 0; i < 4; ++i) {
#pragma unroll
        for (int r = 0; r < 4; ++r) {
          int rl = i * 16 + q * 4 + r;
          T[rl * 68 + cl] =
              __builtin_bit_cast(unsigned short, (_Float16)(acc[i][j][r] + bias));
        }
      }
    }
    int kvcol = cbase - CC + (lane & 15) * 4;    // 4 fp16 per lane
#pragma unroll
    for (int p = 0; p < 16; ++p) {
      int rl = p * 4 + (lane >> 4);
      uint2 v = *(const uint2*)&T[rl * 68 + (lane & 15) * 4];
      long row = rbase + rl;
      if (row < M) *(uint2*)(kvh + row * KVS + kvcol) = v;
    }
  }
}

// ---------------- fused attention: wave = node, fp16 K/V gather + fdot2 ----------
__global__ __launch_bounds__(256) void attn_fused_kernel(const float* __restrict__ Qb,
                                                         const _Float16* __restrict__ kvh,
                                                         const int* __restrict__ row_start,
                                                         const int* __restrict__ csr_src,
                                                         unsigned short* __restrict__ h_hi,
                                                         unsigned short* __restrict__ h_lo,
                                                         int N, int npx) {
  int b = blockIdx.x;
  int nb = (b & 7) * npx + (b >> 3);
  int wave = threadIdx.x >> 6;
  int lane = threadIdx.x & 63;
  int node = nb * 4 + wave;
  if (node >= N) return;
  int s0 = row_start[node], s1 = row_start[node + 1];

  const f32x4 q4 = *(const f32x4*)(Qb + (size_t)node * CC + lane * 4);
  const f16x2 q0 = {(_Float16)q4.x, (_Float16)q4.y};
  const f16x2 q1 = {(_Float16)q4.z, (_Float16)q4.w};

  float m = -1e30f, z = 0.f;
  f32x4 acc = (f32x4)0.f;

  int i = s0;
  for (; i + 8 <= s1; i += 8) {
    int ix[8];
#pragma unroll
    for (int u = 0; u < 8; ++u) ix[u] = csr_src[i + u];
    f16x4 kk[8], vv[8];
#pragma unroll
    for (int u = 0; u < 8; ++u) {
      const _Float16* row = kvh + (size_t)ix[u] * KVS;
      kk[u] = *(const f16x4*)(row + lane * 4);          // K
      vv[u] = *(const f16x4*)(row + 256 + lane * 4);    // V
    }
    float lg[8];
#pragma unroll
    for (int u = 0; u < 8; ++u) {
      float d = qkdot(q0, q1, kk[u]);
#pragma unroll
      for (int off = 1; off < 16; off <<= 1) d += __shfl_xor(d, off, 64);
      lg[u] = d * 0.125f;
    }
    float cm = lg[0];
#pragma unroll
    for (int u = 1; u < 8; ++u) cm = fmaxf(cm, lg[u]);
    float mn = fmaxf(m, cm);
    float sc = __expf(m - mn);
    z *= sc;
    acc *= sc;
    m = mn;
#pragma unroll
    for (int u = 0; u < 8; ++u) {
      float e = __expf(lg[u] - m);
      z += e;
      f32x4 vf = {(float)vv[u].x, (float)vv[u].y, (float)vv[u].z, (float)vv[u].w};
      acc += e * vf;
    }
  }
  for (; i < s1; ++i) {
    int s = csr_src[i];
    const _Float16* row = kvh + (size_t)s * KVS;
    f16x4 k4 = *(const f16x4*)(row + lane * 4);
    f16x4 v4 = *(const f16x4*)(row + 256 + lane * 4);
    float d = qkdot(q0, q1, k4);
#pragma unroll
    for (int off = 1; off < 16; off <<= 1) d += __shfl_xor(d, off, 64);
    float lgs = d * 0.125f;
    float mn = fmaxf(m, lgs);
    float sc = __expf(m - mn);
    float e = __expf(lgs - mn);
    z = z * sc + e;
    f32x4 vf = {(float)v4.x, (float)v4.y, (float)v4.z, (float)v4.w};
    acc = acc * sc + e * vf;
    m = mn;
  }

  float rz = 1.f / (z + 1e-16f);
  float o0 = fmaxf(acc.x * rz, 0.f);
  float o1 = fmaxf(acc.y * rz, 0.f);
  float o2 = fmaxf(acc.z * rz, 0.f);
  float o3 = fmaxf(acc.w * rz, 0.f);
  __bf16 h0 = (__bf16)o0, h1 = (__bf16)o1, h2 = (__bf16)o2, h3 = (__bf16)o3;
  ushort4 ohi = make_ushort4(__builtin_bit_cast(unsigned short, h0),
                             __builtin_bit_cast(unsigned short, h1),
                             __builtin_bit_cast(unsigned short, h2),
                             __builtin_bit_cast(unsigned short, h3));
  ushort4 olo = make_ushort4(__builtin_bit_cast(unsigned short, (__bf16)(o0 - (float)h0)),
                             __builtin_bit_cast(unsigned short, (__bf16)(o1 - (float)h1)),
                             __builtin_bit_cast(unsigned short, (__bf16)(o2 - (float)h2)),
                             __builtin_bit_cast(unsigned short, (__bf16)(o3 - (float)h3)));
  size_t idx = (size_t)node * CC + lane * 4;
  *(ushort4*)(h_hi + idx) = ohi;
  *(ushort4*)(h_lo + idx) = olo;
}

// ---------------- pool: parallel segment-sum with atomics (batch sorted) ----------------
__global__ void pool_kernel(const unsigned short* __restrict__ h_hi,
                            const unsigned short* __restrict__ h_lo,
                            const int* __restrict__ batch,
                            float* __restrict__ gpool, int N) {
  int c = threadIdx.x;
  int n0 = blockIdx.x * 64;
  int n1 = min(n0 + 64, N);
  int cur = batch[n0];
  float acc = 0.f;
  for (int n = n0; n < n1; ++n) {
    int g = batch[n];
    if (g != cur) {
      atomicAdd(&gpool[cur * CC + c], acc);
      acc = 0.f;
      cur = g;
    }
    size_t idx = (size_t)n * CC + c;
    acc += bf2f(h_hi[idx]) + bf2f(h_lo[idx]);
  }
  atomicAdd(&gpool[cur * CC + c], acc);
}

// ---------------- MLP head ----------------
__global__ void head_kernel(const float* __restrict__ gpool, const float* __restrict__ W1,
                            const float* __restrict__ b1, const float* __restrict__ W2,
                            const float* __restrict__ b2, float* __restrict__ out) {
  __shared__ float hid[64];
  int g = blockIdx.x, t = threadIdx.x;
  float acc = b1[t];
  for (int i = 0; i < CC; ++i) acc = fmaf(gpool[g * CC + i], W1[i * 64 + t], acc);
  hid[t] = fmaxf(acc, 0.f);
  __syncthreads();
  if (t < 16) {
    float o = b2[t];
    for (int i = 0; i < 64; ++i) o = fmaf(hid[i], W2[i * 16 + t], o);
    out[g * 16 + t] = o;
  }
}

extern "C" void kernel_launch(void* const* d_in, const int* in_sizes, int n_in,
                              void* d_out, int out_size, void* d_ws, size_t ws_size,
                              hipStream_t stream) {
  const float* x  = (const float*)d_in[0];
  const int* ei   = (const int*)d_in[1];
  const int* batch = (const int*)d_in[2];
  const float* Wq = (const float*)d_in[3];
  const float* bq = (const float*)d_in[4];
  const float* Wk = (const float*)d_in[5];
  const float* bk = (const float*)d_in[6];
  const float* Wv = (const float*)d_in[7];
  const float* bv = (const float*)d_in[8];
  const float* W1 = (const float*)d_in[9];
  const float* b1 = (const float*)d_in[10];
  const float* W2 = (const float*)d_in[11];
  const float* b2 = (const float*)d_in[12];
  float* out = (float*)d_out;

  int N = in_sizes[0] / CC;
  int E = in_sizes[1] / 2;
  int L = in_sizes[3] / (CC * CC);
  const int* src = ei;
  const int* dst = ei + E;

  // workspace budget: keep total < 256 MB (R3 crashed at ~278 MB)
  size_t off = 0;
  auto alloc = [&](size_t bytes) -> void* {
    void* p = (char*)d_ws + off;
    off += (bytes + 255) & ~(size_t)255;
    return p;
  };
  float* Qb = (float*)alloc((size_t)N * CC * 4);                      // 51.2 MB
  _Float16* kvh = (_Float16*)alloc((size_t)N * KVS * 2);              // 51.2 MB
  unsigned short* h_hi = (unsigned short*)alloc((size_t)N * CC * 2);  // 25.6 MB
  unsigned short* h_lo = (unsigned short*)alloc((size_t)N * CC * 2);  // 25.6 MB
  unsigned short* Bth = (unsigned short*)alloc((size_t)L * QKVS * CC * 2);
  unsigned short* Btl = (unsigned short*)alloc((size_t)L * QKVS * CC * 2);
  float* biascat = (float*)alloc((size_t)L * QKVS * 4);
  int* deg = (int*)alloc((size_t)N * 4);
  int* exc = (int*)alloc((size_t)N * 4);
  int* partial = (int*)alloc(SCAN_BS * 4);
  int* row_start = (int*)alloc((size_t)(N + 1) * 4);
  int* cursor = (int*)alloc((size_t)N * 4);
  int* csr_src = (int*)alloc((size_t)E * 4);
  float* gpool = (float*)alloc((size_t)NG * CC * 4);
  // total ~= 160 MB

  // fused prologue: hist | wprep | split (independent; one launch)
  hipMemsetAsync(deg, 0, (size_t)N * 4, stream);
  int eb = (E + 255) / 256;
  int wtot = L * QKVS * CC;
  int nbw = (wtot + 255) / 256;
  int n4 = N * CC / 4;
  int nbs = (n4 + 255) / 256;
  prep_kernel<<<eb + nbw + nbs, 256, 0, stream>>>(dst, deg, E,
                                                  Wq, Wk, Wv, bq, bk, bv,
                                                  Bth, Btl, biascat, L,
                                                  x, h_hi, h_lo, n4, eb, nbw);

  // CSR scan chain
  int nb = (N + SCAN_BS - 1) / SCAN_BS;
  scan1_kernel<<<nb, SCAN_BS, 0, stream>>>(deg, exc, partial, N);
  scan2_kernel<<<1, SCAN_BS, 0, stream>>>(partial, nb);
  scan3_kernel<<<(N + 1 + 255) / 256, 256, 0, stream>>>(exc, partial, row_start, cursor, N, E);
  scatter_kernel<<<eb, 256, 0, stream>>>(src, dst, cursor, csr_src, E);

  // layers
  dim3 gemmGrid(QKVS / 128, (N + 127) / 128);   // bn FAST -> A-tile reuse
  int nblocks = (N + 3) / 4;          // 4 nodes per block (wave = node)
  int npx = (nblocks + 7) / 8;        // blocks per XCD
  int ngrid = npx * 8;
  for (int l = 0; l < L; ++l) {
    qkv_gemm<<<gemmGrid, 256, 0, stream>>>(h_hi, h_lo,
                                           Bth + (size_t)l * QKVS * CC,
                                           Btl + (size_t)l * QKVS * CC,
                                           biascat + (size_t)l * QKVS, Qb, kvh, N);
    attn_fused_kernel<<<ngrid, 256, 0, stream>>>(Qb, kvh, row_start, csr_src,
                                                 h_hi, h_lo, N, npx);
  }

  // pool + head
  hipMemsetAsync(gpool, 0, (size_t)NG * CC * 4, stream);
  pool_kernel<<<(N + 63) / 64, 256, 0, stream>>>(h_hi, h_lo, batch, gpool, N);
  head_kernel<<<NG, 64, 0, stream>>>(gpool, W1, b1, W2, b2, out);
}